// Round 10
// baseline (387.178 us; speedup 1.0000x reference)
//
#include <hip/hip_runtime.h>

// B=4, C=64, H=W=64, N=4096, GROUPS=32 (2 ch/group), R=4.
// ws layout (bytes):
#define STATS_OFF 0                       // [1024][5] fp32 partial sums (bc*4+chunk)
#define AD_OFF    20480                   // [src(3)][b*64+c][2] fp32 (a, d)
#define SEY_OFF   26624                   // [b*64+c] fp32
#define CNT_OFF   28672                   // int: stats-done counter (memset to 0 each call)
#define WQB_OFF   32768                   // bf16 wq*qscale [o][c] 8KB
#define WKB_OFF   40960                   // bf16 wk
#define WVB_OFF   49152                   // bf16 wv
#define Q_OFF     57344                   // [bh][n][c] bf16, 4MB (q pre-scaled)
#define K_OFF     (Q_OFF + 4194304)       // [bh][n][c] bf16, 4MB
#define V_OFF     (K_OFF + 4194304)       // [b][c][n]  bf16, 2MB
#define PO_OFF    (V_OFF + 2097152)       // [bh][js][n][c] bf16 partials, then pl fp32

#define QSCALE 0.18033688f                // 0.125 * log2(e)
// XOR swizzle (8-element granularity) -> balanced LDS bank phases for b128/b64 frag reads
#define SWZ(r) ((((r) & 7) << 3) ^ (((r) & 8) << 1))

typedef __attribute__((ext_vector_type(8))) short  short8;
typedef __attribute__((ext_vector_type(4))) short  s16x4;
typedef __attribute__((ext_vector_type(2))) unsigned int u32x2;
typedef __attribute__((ext_vector_type(4))) float  f32x4;

#if __has_builtin(__builtin_amdgcn_exp2f)
__device__ inline float fexp2(float x) { return __builtin_amdgcn_exp2f(x); }  // raw v_exp_f32
#else
__device__ inline float fexp2(float x) { return exp2f(x); }
#endif

__device__ inline ushort f2b(float f) {   // round-half-up to bf16
  return (ushort)((__float_as_uint(f) + 0x8000u) >> 16);
}
__device__ inline unsigned pack2(float x, float y) {  // bf16(x) | bf16(y)<<16
  unsigned ux = __float_as_uint(x) + 0x8000u;
  unsigned uy = __float_as_uint(y) + 0x8000u;
  return __builtin_amdgcn_perm(uy, ux, 0x07060302);
}
__device__ inline float b2f(ushort u) { return __uint_as_float(((unsigned)u) << 16); }

__device__ inline f32x4 mfma16(short8 a, short8 b, f32x4 c) {
  return __builtin_amdgcn_mfma_f32_16x16x32_bf16(a, b, c, 0, 0, 0);
}

__device__ inline float wsum64(float v) {
  #pragma unroll
  for (int o = 32; o > 0; o >>= 1) v += __shfl_down(v, o, 64);
  return v;
}

// ---------------- kernel 1: stats + weight conversion + (last block) SE/GN prep ----------------
__global__ __launch_bounds__(256) void sc_stats(const float* __restrict__ x1,
                                                const float* __restrict__ x2,
                                                float* __restrict__ stats,
                                                const float* __restrict__ wq,
                                                const float* __restrict__ wk,
                                                const float* __restrict__ wv,
                                                ushort* __restrict__ wqb,
                                                ushort* __restrict__ wkb,
                                                ushort* __restrict__ wvb,
                                                const float* __restrict__ w1,
                                                const float* __restrict__ w2,
                                                const float* __restrict__ gamma,
                                                const float* __restrict__ beta,
                                                float* __restrict__ ad,
                                                float* __restrict__ sey,
                                                int* __restrict__ cnt) {
  int blk = blockIdx.x, t = threadIdx.x;  // 1024 = bc*4 + chunk
  int bc = blk >> 2, chunk = blk & 3;
  const float4* p1 = (const float4*)(x1 + (size_t)bc * 4096 + chunk * 1024);
  const float4* p2 = (const float4*)(x2 + (size_t)bc * 4096 + chunk * 1024);
  float4 a = p1[t], b = p2[t];
  float s1 = a.x + a.y + a.z + a.w;
  float q1 = a.x*a.x + a.y*a.y + a.z*a.z + a.w*a.w;
  float s2 = b.x + b.y + b.z + b.w;
  float q2 = b.x*b.x + b.y*b.y + b.z*b.z + b.w*b.w;
  float p12 = a.x*b.x + a.y*b.y + a.z*b.z + a.w*b.w;
  s1 = wsum64(s1); q1 = wsum64(q1); s2 = wsum64(s2); q2 = wsum64(q2); p12 = wsum64(p12);
  __shared__ float red[4][5];
  int w = t >> 6, ln = t & 63;
  if (ln == 0) { red[w][0] = s1; red[w][1] = q1; red[w][2] = s2; red[w][3] = q2; red[w][4] = p12; }
  __syncthreads();
  if (t < 5) {
    float acc = 0;
    #pragma unroll
    for (int ww = 0; ww < 4; ww++) acc += red[ww][t];
    stats[(size_t)blk * 5 + t] = acc;
  }
  if (blk >= 976) {     // parallel bf16 weight conversion (independent of stats)
    int idx = (blk - 976) * 256 + t;
    int arr = idx >> 12, e = idx & 4095;
    if (arr == 0)      wqb[e] = f2b(wq[e] * QSCALE);
    else if (arr == 1) wkb[e] = f2b(wk[e]);
    else               wvb[e] = f2b(wv[e]);
  }
  // ---- last-arriving block performs the SE/GN prep (release/acquire via fence+atomic) ----
  __threadfence();
  __shared__ int lastFlag;
  if (t == 0) lastFlag = (atomicAdd(cnt, 1) == 1023) ? 1 : 0;
  __syncthreads();
  if (!lastFlag) return;
  __threadfence();     // acquire: all blocks' stats stores visible
  {
    __shared__ float smu[256], sS[3][256], sQ[3][256], sy[16];
    int bb = t >> 6, c = t & 63;
    float t1 = 0, t2 = 0, t3 = 0, t4 = 0, t5 = 0;
    #pragma unroll
    for (int ch = 0; ch < 4; ch++) {
      const float* sp = stats + (size_t)(t * 4 + ch) * 5;
      t1 += sp[0]; t2 += sp[1]; t3 += sp[2]; t4 += sp[3]; t5 += sp[4];
    }
    float sx = t1 + t3, qx = t2 + t4 + 2.f * t5;
    smu[t] = sx * (1.f / 4096.f);
    sS[0][t] = sx; sQ[0][t] = qx; sS[1][t] = t1; sQ[1][t] = t2; sS[2][t] = t3; sQ[2][t] = t4;
    __syncthreads();
    if (t < 16) {
      int b2_ = t >> 2, r = t & 3; float acc = 0.f;
      for (int cc = 0; cc < 64; cc++) acc += w1[r*64+cc] * smu[b2_*64+cc];
      sy[t] = fmaxf(acc, 0.f);
    }
    __syncthreads();
    float acc = 0.f;
    #pragma unroll
    for (int r = 0; r < 4; r++) acc += w2[c*4+r] * sy[bb*4+r];
    sey[t] = 1.f / (1.f + fexp2(-acc * 1.44269504f));
    int prt = t ^ 1;
    float g = gamma[c], bt = beta[c];
    #pragma unroll
    for (int s = 0; s < 3; s++) {
      float S = sS[s][t] + sS[s][prt], Q = sQ[s][t] + sQ[s][prt];
      float mean = S * (1.f / 8192.f);
      float var  = Q * (1.f / 8192.f) - mean * mean;
      float rstd = rsqrtf(var + 1e-6f);
      float av = g * rstd;
      ad[((s*256) + t)*2 + 0] = av;
      ad[((s*256) + t)*2 + 1] = bt - mean * av;
    }
  }
}

// ------------- kernel 2: GN + 1x1 conv projections via MFMA, parallel bias fold -------------
__global__ __launch_bounds__(256) void sc_proj(const float* __restrict__ x1, const float* __restrict__ x2,
    const float* __restrict__ ad,
    const float* __restrict__ wq, const float* __restrict__ bq,
    const float* __restrict__ wk, const float* __restrict__ bk,
    const float* __restrict__ wv, const float* __restrict__ bv,
    const ushort* __restrict__ wqb, const ushort* __restrict__ wkb, const ushort* __restrict__ wvb,
    ushort* __restrict__ qout, ushort* __restrict__ kout, ushort* __restrict__ vout) {
  int pt = blockIdx.x, src = blockIdx.y, b = blockIdx.z, t = threadIdx.x;
  __shared__ ushort xlds[64 * 66];   // xn tile [p][c], bf16
  __shared__ ushort olds[64 * 66];   // output assembly tile
  __shared__ float sd[64], sbias[2][64];
  if (t < 64) sd[t] = ad[((src*256) + b*64 + t)*2 + 1];
  __syncthreads();
  {
    int c = t >> 2, pq = (t & 3) * 16;
    const float* px1 = x1 + ((size_t)(b*64 + c))*4096 + pt*64 + pq;
    const float* px2 = x2 + ((size_t)(b*64 + c))*4096 + pt*64 + pq;
    float av = ad[((src*256) + b*64 + c)*2 + 0];
    #pragma unroll
    for (int k4 = 0; k4 < 4; k4++) {
      float4 v1 = *(const float4*)(px1 + 4*k4);
      float xv[4];
      if (src == 1) { xv[0]=v1.x; xv[1]=v1.y; xv[2]=v1.z; xv[3]=v1.w; }
      else {
        float4 v2 = *(const float4*)(px2 + 4*k4);
        if (src == 2) { xv[0]=v2.x; xv[1]=v2.y; xv[2]=v2.z; xv[3]=v2.w; }
        else { xv[0]=v1.x+v2.x; xv[1]=v1.y+v2.y; xv[2]=v1.z+v2.z; xv[3]=v1.w+v2.w; }
      }
      #pragma unroll
      for (int k = 0; k < 4; k++)
        xlds[(pq + 4*k4 + k)*66 + c] = f2b(av * xv[k]);
    }
  }
  int nbias = (src == 0) ? 64 : 128;
  if (t < nbias) {                   // bias' = W*d + bias (parallel across all 768 blocks)
    int proj = t >> 6, o = t & 63;
    const float* W  = (src == 0) ? wv : (proj == 0 ? wq : wk);
    const float* bs = (src == 0) ? bv : (proj == 0 ? bq : bk);
    float acc = bs[o];
    for (int cc = 0; cc < 64; cc++) acc += W[o*64+cc] * sd[cc];
    if (src != 0 && proj == 0) acc *= QSCALE;
    sbias[proj][o] = acc;
  }
  __syncthreads();
  int wave = t >> 6, lane = t & 63, quad = lane >> 4, l15 = lane & 15;
  int orow = t >> 2, ocol = (t & 3) * 16;   // coalesced write-out mapping
  if (src == 0) {
    const ushort* ap = wvb + (wave*16 + l15)*64 + quad*8;
    short8 a0 = *(const short8*)ap;
    short8 a1 = *(const short8*)(ap + 32);
    f32x4 cinit;
    #pragma unroll
    for (int r = 0; r < 4; r++) cinit[r] = sbias[0][wave*16 + quad*4 + r];
    #pragma unroll
    for (int s = 0; s < 4; s++) {
      const ushort* bp = xlds + (s*16 + l15)*66 + quad*8;
      short8 b0 = *(const short8*)bp;
      short8 b1 = *(const short8*)(bp + 32);
      f32x4 acc = mfma16(a0, b0, cinit);
      acc = mfma16(a1, b1, acc);
      #pragma unroll
      for (int r = 0; r < 4; r++)
        olds[(wave*16 + quad*4 + r)*66 + s*16 + l15] = f2b(acc[r]);   // [o][p]
    }
    __syncthreads();
    uint4 w0 = *(const uint4*)&olds[orow*66 + ocol];
    uint4 w1 = *(const uint4*)&olds[orow*66 + ocol + 8];
    ushort* dst = vout + ((size_t)(b*64 + orow))*4096 + pt*64 + ocol;
    *(uint4*)dst = w0; *(uint4*)(dst + 8) = w1;
  } else {
    int bh = b*2 + (src - 1);
    const ushort* ap = xlds + (wave*16 + l15)*66 + quad*8;
    short8 a0 = *(const short8*)ap;
    short8 a1 = *(const short8*)(ap + 32);
    #pragma unroll
    for (int proj = 0; proj < 2; proj++) {
      const ushort* Wb = proj == 0 ? wqb : wkb;
      ushort* dst = proj == 0 ? qout : kout;
      #pragma unroll
      for (int s = 0; s < 4; s++) {
        const ushort* bp = Wb + (s*16 + l15)*64 + quad*8;
        short8 b0 = *(const short8*)bp;
        short8 b1 = *(const short8*)(bp + 32);
        float bb = sbias[proj][s*16 + l15];
        f32x4 acc = {bb, bb, bb, bb};
        acc = mfma16(a0, b0, acc);
        acc = mfma16(a1, b1, acc);
        #pragma unroll
        for (int r = 0; r < 4; r++)
          olds[(wave*16 + quad*4 + r)*66 + s*16 + l15] = f2b(acc[r]);  // [p][o]
      }
      __syncthreads();
      uint4 w0 = *(const uint4*)&olds[orow*66 + ocol];
      uint4 w1 = *(const uint4*)&olds[orow*66 + ocol + 8];
      ushort* dp = dst + ((size_t)bh*4096 + pt*64 + orow)*64 + ocol;
      *(uint4*)dp = w0; *(uint4*)(dp + 8) = w1;
      if (proj == 0) __syncthreads();   // olds reused by proj 1
    }
  }
}

// ------------- kernel 3: flash attention, 128-thread blocks (2 waves), i=64/wave -------------
// grid 8*32*njs: bh = blk&7 (XCD-local K/V), rest = blk>>3: js = rest&(njs-1), itile = rest>>jsbits.
// 2-wave blocks quadruple the independent barrier domains per CU vs R8's 4-wave blocks
// (same 8 waves/CU): barrier drains stall 1/4 of the CU instead of 1/2.
// launch_bounds(128,3): VGPR cap 170, est ~150 — no spill (R6 lesson); >=6 blocks/CU allowed.
__global__ __launch_bounds__(128, 3) void sc_flash(const ushort* __restrict__ qg,
                                                   const ushort* __restrict__ kg,
                                                   const ushort* __restrict__ vg,
                                                   ushort* __restrict__ po,
                                                   float* __restrict__ pl,
                                                   int jsbits) {
  int blk = blockIdx.x;
  int bh = blk & 7, rest = blk >> 3;
  int njs = 1 << jsbits, njt = 64 >> jsbits;
  int js = rest & (njs - 1), itile = rest >> jsbits;   // itile 0..31
  int jbase = js * (njt << 6);
  int b = bh >> 1;
  int t = threadIdx.x, wave = t >> 6, lane = t & 63, quad = lane >> 4, l15 = lane & 15;
  int i0 = itile * 128 + wave * 64;

  __shared__ ushort Klds[64 * 64];       // [j][c^swz(j)]
  __shared__ ushort Vlds[64 * 64];       // [c][j^swz(c)]

  // Q B-frags (B[k=c][n=i]): lane -> i=l15, c=quad*8(+32); four i-blocks of 16
  short8 Qb[4][2];
  #pragma unroll
  for (int ib = 0; ib < 4; ib++) {
    const ushort* qp = qg + ((size_t)bh * 4096 + i0 + ib * 16 + l15) * 64 + quad * 8;
    Qb[ib][0] = *(const short8*)qp;
    Qb[ib][1] = *(const short8*)(qp + 32);
  }

  f32x4 O[4][4]; const f32x4 zero4 = {0.f, 0.f, 0.f, 0.f};
  #pragma unroll
  for (int ib = 0; ib < 4; ib++)
    #pragma unroll
    for (int cb = 0; cb < 4; cb++) O[ib][cb] = zero4;
  float lsum[4] = {0.f, 0.f, 0.f, 0.f};

  // staging (128 threads): thread -> row t>>1 (j for K, c for V), 64B half-row (t&1)*32
  int sr = t >> 1, sc = (t & 1) * 32;
  int swzs = SWZ(sr);
  int swzl = SWZ(l15);
  const ushort* ksrc = kg + ((size_t)bh * 4096 + jbase + sr) * 64 + sc;
  const ushort* vsrc = vg + ((size_t)(b * 64 + sr)) * 4096 + jbase + sc;
  ushort* kbase = Klds + sr * 64;
  ushort* vbase = Vlds + sr * 64;

  // register prefetch of tile 0 (4 uint4 per matrix per thread)
  uint4 kr[4], vr[4];
  #pragma unroll
  for (int m = 0; m < 4; m++) { kr[m] = *(const uint4*)(ksrc + 8*m); vr[m] = *(const uint4*)(vsrc + 8*m); }
  ksrc += 4096; vsrc += 64;

  #pragma unroll 1
  for (int jt = 0; jt < njt; jt++) {
    __syncthreads();                     // prior iteration's LDS reads done
    #pragma unroll
    for (int m = 0; m < 4; m++) {
      *(uint4*)(kbase + ((sc + 8*m) ^ swzs)) = kr[m];
      *(uint4*)(vbase + ((sc + 8*m) ^ swzs)) = vr[m];
    }
    __syncthreads();
    if (jt + 1 < njt) {                  // issue next tile's loads; land during compute
      #pragma unroll
      for (int m = 0; m < 4; m++) { kr[m] = *(const uint4*)(ksrc + 8*m); vr[m] = *(const uint4*)(vsrc + 8*m); }
      ksrc += 4096; vsrc += 64;
    }

    #pragma unroll
    for (int s = 0; s < 4; s++) {
      // S^T = K Q^T : D[j = s*16+quad*4+r][i = ib*16+l15]
      int rowK = (s * 16 + l15) * 64;
      short8 ka0 = *(const short8*)&Klds[rowK + ((quad * 8) ^ swzl)];
      short8 ka1 = *(const short8*)&Klds[rowK + ((quad * 8 + 32) ^ swzl)];
      f32x4 S[4];
      #pragma unroll
      for (int ib = 0; ib < 4; ib++) {
        f32x4 acc = mfma16(ka0, Qb[ib][0], zero4);
        S[ib] = mfma16(ka1, Qb[ib][1], acc);
      }
      // V B-frags: B[k = quad*4+idx][n -> c = cb*16+l15]
      s16x4 vbf[4];
      #pragma unroll
      for (int cb = 0; cb < 4; cb++)
        vbf[cb] = *(const s16x4*)&Vlds[(cb * 16 + l15) * 64 + ((s * 16 + quad * 4) ^ swzl)];
      // P = exp2(S); accumulate l; O += P V via 16x16x16_1k (A = P in-register)
      #pragma unroll
      for (int ib = 0; ib < 4; ib++) {
        float p0 = fexp2(S[ib][0]);
        float p1 = fexp2(S[ib][1]);
        float p2 = fexp2(S[ib][2]);
        float p3 = fexp2(S[ib][3]);
        lsum[ib] += (p0 + p1) + (p2 + p3);
        u32x2 wpk = {pack2(p0, p1), pack2(p2, p3)};
        s16x4 Pb = __builtin_bit_cast(s16x4, wpk);
        #pragma unroll
        for (int cb = 0; cb < 4; cb++)
          O[ib][cb] = __builtin_amdgcn_mfma_f32_16x16x16bf16_1k(Pb, vbf[cb], O[ib][cb], 0, 0, 0);
      }
    }
  }

  // epilogue: unnormalized O partials (bf16) + l partials
  // O[ib][cb][r]: i = i0 + ib*16 + quad*4 + r, c = cb*16 + l15
  size_t slice = (size_t)(bh * njs + js) * 4096;
  #pragma unroll
  for (int ib = 0; ib < 4; ib++) {
    float lv = lsum[ib];
    lv += __shfl_xor(lv, 16, 64);
    lv += __shfl_xor(lv, 32, 64);
    if (quad == 0) pl[slice + i0 + ib * 16 + l15] = lv;
    #pragma unroll
    for (int cb = 0; cb < 4; cb++)
      #pragma unroll
      for (int r = 0; r < 4; r++)
        po[(slice + i0 + ib * 16 + quad * 4 + r) * 64 + cb * 16 + l15] = f2b(O[ib][cb][r]);
  }
}

// ------------- kernel 4: partial reduce + normalize + SE-gated blend -------------
// grid (64 itile, 4 b, 2 chalf)
__global__ __launch_bounds__(256) void sc_combine(const float* __restrict__ x1, const float* __restrict__ x2,
                                                  const ushort* __restrict__ po, const float* __restrict__ pl,
                                                  const float* __restrict__ sey,
                                                  float* __restrict__ out, int jsbits) {
  int njs = 1 << jsbits;
  int itile = blockIdx.x, b = blockIdx.y, ch = blockIdx.z, t = threadIdx.x;
  __shared__ float hl[2][32 * 65];   // [head][c-local][p]
  #pragma unroll
  for (int head = 0; head < 2; head++) {
    int bh = b * 2 + head;
    int i = t >> 2, c8 = (t & 3) * 8;
    float sum[8];
    #pragma unroll
    for (int k = 0; k < 8; k++) sum[k] = 0.f;
    float lacc = 0.f;
    for (int js = 0; js < njs; js++) {
      size_t base = ((size_t)(bh * njs + js)) * 4096;
      uint4 u = *(const uint4*)(po + base * 64 + (size_t)(itile * 64 + i) * 64 + ch * 32 + c8);
      const ushort* us = (const ushort*)&u;
      #pragma unroll
      for (int k = 0; k < 8; k++) sum[k] += b2f(us[k]);
      lacc += pl[base + itile * 64 + i];
    }
    float inv = 1.f / lacc;
    #pragma unroll
    for (int k = 0; k < 8; k++) hl[head][(c8 + k) * 65 + i] = sum[k] * inv;
  }
  __syncthreads();
  #pragma unroll
  for (int it = 0; it < 8; it++) {
    int idx = it * 256 + t;
    int cl = idx >> 6, p = idx & 63;
    int c = ch * 32 + cl;
    size_t gi = ((size_t)(b * 64 + c)) * 4096 + itile * 64 + p;
    float xv = x1[gi] + x2[gi];
    float sig = 1.f / (1.f + fexp2(-xv * sey[b * 64 + c] * 1.44269504f));
    float h1 = hl[0][cl * 65 + p], h2 = hl[1][cl * 65 + p];
    out[gi] = 2.f * (h1 * sig + h2 * (1.f - sig));
  }
}

extern "C" void kernel_launch(void* const* d_in, const int* in_sizes, int n_in,
                              void* d_out, int out_size, void* d_ws, size_t ws_size,
                              hipStream_t stream) {
  (void)in_sizes; (void)n_in; (void)out_size;
  const float* x1    = (const float*)d_in[0];
  const float* x2    = (const float*)d_in[1];
  const float* se_w1 = (const float*)d_in[2];
  const float* se_w2 = (const float*)d_in[3];
  const float* gamma = (const float*)d_in[4];
  const float* beta  = (const float*)d_in[5];
  const float* wq    = (const float*)d_in[6];
  const float* bq    = (const float*)d_in[7];
  const float* wk    = (const float*)d_in[8];
  const float* bk    = (const float*)d_in[9];
  const float* wv    = (const float*)d_in[10];
  const float* bv    = (const float*)d_in[11];
  float* out = (float*)d_out;
  char* ws = (char*)d_ws;
  float*  stats = (float*)(ws + STATS_OFF);
  float*  ad    = (float*)(ws + AD_OFF);
  float*  sey   = (float*)(ws + SEY_OFF);
  int*    cnt   = (int*)(ws + CNT_OFF);
  ushort* wqb   = (ushort*)(ws + WQB_OFF);
  ushort* wkb   = (ushort*)(ws + WKB_OFF);
  ushort* wvb   = (ushort*)(ws + WVB_OFF);
  ushort* qb    = (ushort*)(ws + Q_OFF);
  ushort* kb    = (ushort*)(ws + K_OFF);
  ushort* vb    = (ushort*)(ws + V_OFF);

  // js split: largest of {8,4,2} whose partials fit the workspace (ws_size fixed per process).
  int jsbits = 1;
  for (int jb = 3; jb >= 2; jb--) {
    size_t need = (size_t)PO_OFF + ((size_t)8 * 4096 * 64 * 2 + (size_t)8 * 4096 * 4) * (1u << jb);
    if (ws_size >= need) { jsbits = jb; break; }
  }
  int njs = 1 << jsbits;
  ushort* pob = (ushort*)(ws + PO_OFF);
  float*  plb = (float*)(ws + PO_OFF + (size_t)8 * njs * 4096 * 64 * 2);

  hipMemsetAsync(cnt, 0, sizeof(int), stream);   // ws is 0xAA-poisoned each call
  sc_stats  <<<1024, 256, 0, stream>>>(x1, x2, stats, wq, wk, wv, wqb, wkb, wvb,
                                       se_w1, se_w2, gamma, beta, ad, sey, cnt);
  sc_proj   <<<dim3(64, 3, 4), 256, 0, stream>>>(x1, x2, ad,
                                                 wq, bq, wk, bk, wv, bv,
                                                 wqb, wkb, wvb, qb, kb, vb);
  sc_flash  <<<8 * 32 * njs, 128, 0, stream>>>(qb, kb, vb, pob, plb, jsbits);
  sc_combine<<<dim3(64, 4, 2), 256, 0, stream>>>(x1, x2, pob, plb, sey, out, jsbits);
}

// Round 11
// 346.709 us; speedup vs baseline: 1.1167x; 1.1167x over previous
//
#include <hip/hip_runtime.h>

// B=4, C=64, H=W=64, N=4096, GROUPS=32 (2 ch/group), R=4.
// ws layout (bytes):
#define STATS_OFF 0                       // [1024][5] fp32 partial sums (bc*4+chunk)
#define AD_OFF    20480                   // [src(3)][b*64+c][2] fp32 (a, d)
#define SEY_OFF   26624                   // [b*64+c] fp32
#define CCNT_OFF  28672                   // int[64]: combine last-arrival counters (zeroed by sc_prep)
#define WQB_OFF   32768                   // bf16 wq*qscale [o][c] 8KB
#define WKB_OFF   40960                   // bf16 wk
#define WVB_OFF   49152                   // bf16 wv
#define Q_OFF     57344                   // [bh][n][c] bf16, 4MB (q pre-scaled)
#define K_OFF     (Q_OFF + 4194304)       // [bh][n][c] bf16, 4MB
#define V_OFF     (K_OFF + 4194304)       // [b][c][n]  bf16, 2MB
#define PO_OFF    (V_OFF + 2097152)       // [bh][js][n][c] bf16 partials, then pl fp32

#define QSCALE 0.18033688f                // 0.125 * log2(e)
// XOR swizzle (8-element granularity) -> balanced LDS bank phases for b128/b64 frag reads
#define SWZ(r) ((((r) & 7) << 3) ^ (((r) & 8) << 1))

typedef __attribute__((ext_vector_type(8))) short  short8;
typedef __attribute__((ext_vector_type(4))) short  s16x4;
typedef __attribute__((ext_vector_type(2))) unsigned int u32x2;
typedef __attribute__((ext_vector_type(4))) float  f32x4;

#if __has_builtin(__builtin_amdgcn_exp2f)
__device__ inline float fexp2(float x) { return __builtin_amdgcn_exp2f(x); }  // raw v_exp_f32
#else
__device__ inline float fexp2(float x) { return exp2f(x); }
#endif

__device__ inline ushort f2b(float f) {   // round-half-up to bf16
  return (ushort)((__float_as_uint(f) + 0x8000u) >> 16);
}
__device__ inline unsigned pack2(float x, float y) {  // bf16(x) | bf16(y)<<16
  unsigned ux = __float_as_uint(x) + 0x8000u;
  unsigned uy = __float_as_uint(y) + 0x8000u;
  return __builtin_amdgcn_perm(uy, ux, 0x07060302);
}
__device__ inline float b2f(ushort u) { return __uint_as_float(((unsigned)u) << 16); }

__device__ inline f32x4 mfma16(short8 a, short8 b, f32x4 c) {
  return __builtin_amdgcn_mfma_f32_16x16x32_bf16(a, b, c, 0, 0, 0);
}

__device__ inline float wsum64(float v) {
  #pragma unroll
  for (int o = 32; o > 0; o >>= 1) v += __shfl_down(v, o, 64);
  return v;
}

// ---------------- kernel 1: per-(b,c) partial sums + bf16 weight conversion ----------------
__global__ __launch_bounds__(256) void sc_stats(const float* __restrict__ x1,
                                                const float* __restrict__ x2,
                                                float* __restrict__ stats,
                                                const float* __restrict__ wq,
                                                const float* __restrict__ wk,
                                                const float* __restrict__ wv,
                                                ushort* __restrict__ wqb,
                                                ushort* __restrict__ wkb,
                                                ushort* __restrict__ wvb) {
  int blk = blockIdx.x, t = threadIdx.x;  // 1024 = bc*4 + chunk
  int bc = blk >> 2, chunk = blk & 3;
  const float4* p1 = (const float4*)(x1 + (size_t)bc * 4096 + chunk * 1024);
  const float4* p2 = (const float4*)(x2 + (size_t)bc * 4096 + chunk * 1024);
  float4 a = p1[t], b = p2[t];
  float s1 = a.x + a.y + a.z + a.w;
  float q1 = a.x*a.x + a.y*a.y + a.z*a.z + a.w*a.w;
  float s2 = b.x + b.y + b.z + b.w;
  float q2 = b.x*b.x + b.y*b.y + b.z*b.z + b.w*b.w;
  float p12 = a.x*b.x + a.y*b.y + a.z*b.z + a.w*b.w;
  s1 = wsum64(s1); q1 = wsum64(q1); s2 = wsum64(s2); q2 = wsum64(q2); p12 = wsum64(p12);
  __shared__ float red[4][5];
  int w = t >> 6, ln = t & 63;
  if (ln == 0) { red[w][0] = s1; red[w][1] = q1; red[w][2] = s2; red[w][3] = q2; red[w][4] = p12; }
  __syncthreads();
  if (t < 5) {
    float acc = 0;
    #pragma unroll
    for (int ww = 0; ww < 4; ww++) acc += red[ww][t];
    stats[(size_t)blk * 5 + t] = acc;
  }
  if (blk >= 976) {     // parallel bf16 weight conversion (independent of stats)
    int idx = (blk - 976) * 256 + t;
    int arr = idx >> 12, e = idx & 4095;
    if (arr == 0)      wqb[e] = f2b(wq[e] * QSCALE);
    else if (arr == 1) wkb[e] = f2b(wk[e]);
    else               wvb[e] = f2b(wv[e]);
  }
}

// ------------- kernel 2: stats reduce + SE MLP + GN fold + zero combine counters -------------
__global__ __launch_bounds__(256) void sc_prep(const float* __restrict__ stats,
                                               const float* __restrict__ w1,
                                               const float* __restrict__ w2,
                                               const float* __restrict__ gamma,
                                               const float* __restrict__ beta,
                                               float* __restrict__ ad, float* __restrict__ sey,
                                               int* __restrict__ ccnt) {
  int t = threadIdx.x; int b = t >> 6, c = t & 63;
  if (t < 64) ccnt[t] = 0;   // visible to sc_flash via stream ordering
  float s1 = 0, q1 = 0, s2 = 0, q2 = 0, p12 = 0;
  #pragma unroll
  for (int ch = 0; ch < 4; ch++) {
    const float* sp = stats + (size_t)(t * 4 + ch) * 5;
    s1 += sp[0]; q1 += sp[1]; s2 += sp[2]; q2 += sp[3]; p12 += sp[4];
  }
  float sx = s1 + s2, qx = q1 + q2 + 2.f * p12;
  __shared__ float smu[256], sS[3][256], sQ[3][256], sy[16];
  smu[t] = sx * (1.f / 4096.f);
  sS[0][t] = sx; sQ[0][t] = qx; sS[1][t] = s1; sQ[1][t] = q1; sS[2][t] = s2; sQ[2][t] = q2;
  __syncthreads();
  if (t < 16) {
    int bb = t >> 2, r = t & 3; float acc = 0.f;
    for (int cc = 0; cc < 64; cc++) acc += w1[r*64+cc] * smu[bb*64+cc];
    sy[t] = fmaxf(acc, 0.f);
  }
  __syncthreads();
  float acc = 0.f;
  #pragma unroll
  for (int r = 0; r < 4; r++) acc += w2[c*4+r] * sy[b*4+r];
  sey[t] = 1.f / (1.f + fexp2(-acc * 1.44269504f));
  int prt = t ^ 1;
  float g = gamma[c], bt = beta[c];
  #pragma unroll
  for (int s = 0; s < 3; s++) {
    float S = sS[s][t] + sS[s][prt], Q = sQ[s][t] + sQ[s][prt];
    float mean = S * (1.f / 8192.f);
    float var  = Q * (1.f / 8192.f) - mean * mean;
    float rstd = rsqrtf(var + 1e-6f);
    float a = g * rstd;
    ad[((s*256) + t)*2 + 0] = a;
    ad[((s*256) + t)*2 + 1] = bt - mean * a;
  }
}

// ------------- kernel 3: GN + 1x1 conv projections via MFMA, parallel bias fold -------------
__global__ __launch_bounds__(256) void sc_proj(const float* __restrict__ x1, const float* __restrict__ x2,
    const float* __restrict__ ad,
    const float* __restrict__ wq, const float* __restrict__ bq,
    const float* __restrict__ wk, const float* __restrict__ bk,
    const float* __restrict__ wv, const float* __restrict__ bv,
    const ushort* __restrict__ wqb, const ushort* __restrict__ wkb, const ushort* __restrict__ wvb,
    ushort* __restrict__ qout, ushort* __restrict__ kout, ushort* __restrict__ vout) {
  int pt = blockIdx.x, src = blockIdx.y, b = blockIdx.z, t = threadIdx.x;
  __shared__ ushort xlds[64 * 66];   // xn tile [p][c], bf16
  __shared__ ushort olds[64 * 66];   // output assembly tile
  __shared__ float sd[64], sbias[2][64];
  if (t < 64) sd[t] = ad[((src*256) + b*64 + t)*2 + 1];
  __syncthreads();
  {
    int c = t >> 2, pq = (t & 3) * 16;
    const float* px1 = x1 + ((size_t)(b*64 + c))*4096 + pt*64 + pq;
    const float* px2 = x2 + ((size_t)(b*64 + c))*4096 + pt*64 + pq;
    float av = ad[((src*256) + b*64 + c)*2 + 0];
    #pragma unroll
    for (int k4 = 0; k4 < 4; k4++) {
      float4 v1 = *(const float4*)(px1 + 4*k4);
      float xv[4];
      if (src == 1) { xv[0]=v1.x; xv[1]=v1.y; xv[2]=v1.z; xv[3]=v1.w; }
      else {
        float4 v2 = *(const float4*)(px2 + 4*k4);
        if (src == 2) { xv[0]=v2.x; xv[1]=v2.y; xv[2]=v2.z; xv[3]=v2.w; }
        else { xv[0]=v1.x+v2.x; xv[1]=v1.y+v2.y; xv[2]=v1.z+v2.z; xv[3]=v1.w+v2.w; }
      }
      #pragma unroll
      for (int k = 0; k < 4; k++)
        xlds[(pq + 4*k4 + k)*66 + c] = f2b(av * xv[k]);
    }
  }
  int nbias = (src == 0) ? 64 : 128;
  if (t < nbias) {                   // bias' = W*d + bias (parallel across all 768 blocks)
    int proj = t >> 6, o = t & 63;
    const float* W  = (src == 0) ? wv : (proj == 0 ? wq : wk);
    const float* bs = (src == 0) ? bv : (proj == 0 ? bq : bk);
    float acc = bs[o];
    for (int cc = 0; cc < 64; cc++) acc += W[o*64+cc] * sd[cc];
    if (src != 0 && proj == 0) acc *= QSCALE;
    sbias[proj][o] = acc;
  }
  __syncthreads();
  int wave = t >> 6, lane = t & 63, quad = lane >> 4, l15 = lane & 15;
  int orow = t >> 2, ocol = (t & 3) * 16;   // coalesced write-out mapping
  if (src == 0) {
    const ushort* ap = wvb + (wave*16 + l15)*64 + quad*8;
    short8 a0 = *(const short8*)ap;
    short8 a1 = *(const short8*)(ap + 32);
    f32x4 cinit;
    #pragma unroll
    for (int r = 0; r < 4; r++) cinit[r] = sbias[0][wave*16 + quad*4 + r];
    #pragma unroll
    for (int s = 0; s < 4; s++) {
      const ushort* bp = xlds + (s*16 + l15)*66 + quad*8;
      short8 b0 = *(const short8*)bp;
      short8 b1 = *(const short8*)(bp + 32);
      f32x4 acc = mfma16(a0, b0, cinit);
      acc = mfma16(a1, b1, acc);
      #pragma unroll
      for (int r = 0; r < 4; r++)
        olds[(wave*16 + quad*4 + r)*66 + s*16 + l15] = f2b(acc[r]);   // [o][p]
    }
    __syncthreads();
    uint4 w0 = *(const uint4*)&olds[orow*66 + ocol];
    uint4 w1 = *(const uint4*)&olds[orow*66 + ocol + 8];
    ushort* dst = vout + ((size_t)(b*64 + orow))*4096 + pt*64 + ocol;
    *(uint4*)dst = w0; *(uint4*)(dst + 8) = w1;
  } else {
    int bh = b*2 + (src - 1);
    const ushort* ap = xlds + (wave*16 + l15)*66 + quad*8;
    short8 a0 = *(const short8*)ap;
    short8 a1 = *(const short8*)(ap + 32);
    #pragma unroll
    for (int proj = 0; proj < 2; proj++) {
      const ushort* Wb = proj == 0 ? wqb : wkb;
      ushort* dst = proj == 0 ? qout : kout;
      #pragma unroll
      for (int s = 0; s < 4; s++) {
        const ushort* bp = Wb + (s*16 + l15)*64 + quad*8;
        short8 b0 = *(const short8*)bp;
        short8 b1 = *(const short8*)(bp + 32);
        float bb = sbias[proj][s*16 + l15];
        f32x4 acc = {bb, bb, bb, bb};
        acc = mfma16(a0, b0, acc);
        acc = mfma16(a1, b1, acc);
        #pragma unroll
        for (int r = 0; r < 4; r++)
          olds[(wave*16 + quad*4 + r)*66 + s*16 + l15] = f2b(acc[r]);  // [p][o]
      }
      __syncthreads();
      uint4 w0 = *(const uint4*)&olds[orow*66 + ocol];
      uint4 w1 = *(const uint4*)&olds[orow*66 + ocol + 8];
      ushort* dp = dst + ((size_t)bh*4096 + pt*64 + orow)*64 + ocol;
      *(uint4*)dp = w0; *(uint4*)(dp + 8) = w1;
      if (proj == 0) __syncthreads();   // olds reused by proj 1
    }
  }
}

// ------------- kernel 4: flash attention (R8 body) + fused last-arrival combine -------------
// grid 8*16*njs: bh = blk&7, rest = blk>>3: js = rest&(njs-1), itile = rest>>jsbits (256 rows).
// After the po/pl epilogue, the 16th (=2*njs) arriving block for (b, itile) performs the
// partial-reduce + SE-gated blend for those 256 rows (deadlock-free last-arrival pattern).
// launch_bounds(256,2): empirical VGPR cap 512/(2*2)=128; R8 body used 108 — no spill.
__global__ __launch_bounds__(256, 2) void sc_flash(const ushort* __restrict__ qg,
                                                   const ushort* __restrict__ kg,
                                                   const ushort* __restrict__ vg,
                                                   const float* __restrict__ x1,
                                                   const float* __restrict__ x2,
                                                   const float* __restrict__ sey,
                                                   ushort* __restrict__ po,
                                                   float* __restrict__ pl,
                                                   int* __restrict__ ccnt,
                                                   float* __restrict__ out,
                                                   int jsbits) {
  int blk = blockIdx.x;
  int bh = blk & 7, rest = blk >> 3;
  int njs = 1 << jsbits, njt = 64 >> jsbits;
  int js = rest & (njs - 1), itile = rest >> jsbits;   // itile 0..15 (256 rows each)
  int jbase = js * (njt << 6);
  int b = bh >> 1;
  int t = threadIdx.x, wave = t >> 6, lane = t & 63, quad = lane >> 4, l15 = lane & 15;
  int i0 = itile * 256 + wave * 64;

  __shared__ __align__(16) char smem[16640];   // union: flash K/V (16384) | combine hl (16640)
  ushort* Klds = (ushort*)smem;            // [j][c^swz(j)] 8192B
  ushort* Vlds = (ushort*)(smem + 8192);   // [c][j^swz(c)] 8192B

  // Q B-frags (B[k=c][n=i]): lane -> i=l15, c=quad*8(+32); four i-blocks of 16
  short8 Qb[4][2];
  #pragma unroll
  for (int ib = 0; ib < 4; ib++) {
    const ushort* qp = qg + ((size_t)bh * 4096 + i0 + ib * 16 + l15) * 64 + quad * 8;
    Qb[ib][0] = *(const short8*)qp;
    Qb[ib][1] = *(const short8*)(qp + 32);
  }

  f32x4 O[4][4]; const f32x4 zero4 = {0.f, 0.f, 0.f, 0.f};
  #pragma unroll
  for (int ib = 0; ib < 4; ib++)
    #pragma unroll
    for (int cb = 0; cb < 4; cb++) O[ib][cb] = zero4;
  float lsum[4] = {0.f, 0.f, 0.f, 0.f};

  // staging: thread -> row t>>2 (j for K, c for V), 32B chunk (t&3)*16, swizzled dest
  int sr = t >> 2, sc = (t & 3) * 16;
  int swzs = SWZ(sr);
  int swzl = SWZ(l15);
  const ushort* ksrc = kg + ((size_t)bh * 4096 + jbase + sr) * 64 + sc;
  const ushort* vsrc = vg + ((size_t)(b * 64 + sr)) * 4096 + jbase + sc;
  ushort* kd0 = Klds + sr * 64 + (sc ^ swzs);
  ushort* kd1 = Klds + sr * 64 + ((sc + 8) ^ swzs);
  ushort* vd0 = Vlds + sr * 64 + (sc ^ swzs);
  ushort* vd1 = Vlds + sr * 64 + ((sc + 8) ^ swzs);

  // register prefetch of tile 0
  uint4 kr0 = *(const uint4*)ksrc, kr1 = *(const uint4*)(ksrc + 8);
  uint4 vr0 = *(const uint4*)vsrc, vr1 = *(const uint4*)(vsrc + 8);
  ksrc += 4096; vsrc += 64;

  #pragma unroll 1
  for (int jt = 0; jt < njt; jt++) {
    __syncthreads();                     // prior iteration's LDS reads done
    *(uint4*)kd0 = kr0; *(uint4*)kd1 = kr1;
    *(uint4*)vd0 = vr0; *(uint4*)vd1 = vr1;
    __syncthreads();
    if (jt + 1 < njt) {                  // issue next tile's loads; land during compute
      kr0 = *(const uint4*)ksrc; kr1 = *(const uint4*)(ksrc + 8);
      vr0 = *(const uint4*)vsrc; vr1 = *(const uint4*)(vsrc + 8);
      ksrc += 4096; vsrc += 64;
    }

    #pragma unroll
    for (int s = 0; s < 4; s++) {
      // S^T = K Q^T : D[j = s*16+quad*4+r][i = ib*16+l15]
      int rowK = (s * 16 + l15) * 64;
      short8 ka0 = *(const short8*)&Klds[rowK + ((quad * 8) ^ swzl)];
      short8 ka1 = *(const short8*)&Klds[rowK + ((quad * 8 + 32) ^ swzl)];
      f32x4 S[4];
      #pragma unroll
      for (int ib = 0; ib < 4; ib++) {
        f32x4 acc = mfma16(ka0, Qb[ib][0], zero4);
        S[ib] = mfma16(ka1, Qb[ib][1], acc);
      }
      // V B-frags: B[k = quad*4+idx][n -> c = cb*16+l15]
      s16x4 vbf[4];
      #pragma unroll
      for (int cb = 0; cb < 4; cb++)
        vbf[cb] = *(const s16x4*)&Vlds[(cb * 16 + l15) * 64 + ((s * 16 + quad * 4) ^ swzl)];
      // P = exp2(S); accumulate l; O += P V via 16x16x16_1k (A = P in-register)
      #pragma unroll
      for (int ib = 0; ib < 4; ib++) {
        float p0 = fexp2(S[ib][0]);
        float p1 = fexp2(S[ib][1]);
        float p2 = fexp2(S[ib][2]);
        float p3 = fexp2(S[ib][3]);
        lsum[ib] += (p0 + p1) + (p2 + p3);
        u32x2 wpk = {pack2(p0, p1), pack2(p2, p3)};
        s16x4 Pb = __builtin_bit_cast(s16x4, wpk);
        #pragma unroll
        for (int cb = 0; cb < 4; cb++)
          O[ib][cb] = __builtin_amdgcn_mfma_f32_16x16x16bf16_1k(Pb, vbf[cb], O[ib][cb], 0, 0, 0);
      }
    }
  }

  // epilogue: unnormalized O partials (bf16) + l partials
  size_t slice = (size_t)(bh * njs + js) * 4096;
  #pragma unroll
  for (int ib = 0; ib < 4; ib++) {
    float lv = lsum[ib];
    lv += __shfl_xor(lv, 16, 64);
    lv += __shfl_xor(lv, 32, 64);
    if (quad == 0) pl[slice + i0 + ib * 16 + l15] = lv;
    #pragma unroll
    for (int cb = 0; cb < 4; cb++)
      #pragma unroll
      for (int r = 0; r < 4; r++)
        po[(slice + i0 + ib * 16 + quad * 4 + r) * 64 + cb * 16 + l15] = f2b(O[ib][cb][r]);
  }

  // ---- fused combine: 16th (=2*njs) arrival for (b, itile) reduces + blends 256 rows ----
  __threadfence();                       // release po/pl
  __shared__ int lastFlag;
  if (t == 0) lastFlag = (atomicAdd(&ccnt[b * 16 + itile], 1) == 2 * njs - 1) ? 1 : 0;
  __syncthreads();                       // broadcast flag; also: all waves done with K/V LDS
  if (!lastFlag) return;
  __threadfence();                       // acquire all producers' po/pl
  float (*hl)[32 * 65] = (float (*)[32 * 65])smem;   // 16640B, reuses flash LDS
  for (int sub = 0; sub < 4; sub++) {
    int it64 = itile * 4 + sub;
    for (int ch = 0; ch < 2; ch++) {
      __syncthreads();                   // hl reuse across iterations
      #pragma unroll
      for (int head = 0; head < 2; head++) {
        int bh2 = b * 2 + head;
        int i = t >> 2, c8 = (t & 3) * 8;
        float sum[8];
        #pragma unroll
        for (int k = 0; k < 8; k++) sum[k] = 0.f;
        float lacc = 0.f;
        for (int js2 = 0; js2 < njs; js2++) {
          size_t base = ((size_t)(bh2 * njs + js2)) * 4096;
          uint4 u = *(const uint4*)(po + base * 64 + (size_t)(it64 * 64 + i) * 64 + ch * 32 + c8);
          const ushort* us = (const ushort*)&u;
          #pragma unroll
          for (int k = 0; k < 8; k++) sum[k] += b2f(us[k]);
          lacc += pl[base + it64 * 64 + i];
        }
        float inv = 1.f / lacc;
        #pragma unroll
        for (int k = 0; k < 8; k++) hl[head][(c8 + k) * 65 + i] = sum[k] * inv;
      }
      __syncthreads();
      #pragma unroll
      for (int it = 0; it < 8; it++) {
        int idx = it * 256 + t;
        int cl = idx >> 6, p = idx & 63;
        int c = ch * 32 + cl;
        size_t gi = ((size_t)(b * 64 + c)) * 4096 + it64 * 64 + p;
        float xv = x1[gi] + x2[gi];
        float sig = 1.f / (1.f + fexp2(-xv * sey[b * 64 + c] * 1.44269504f));
        float h1 = hl[0][cl * 65 + p], h2 = hl[1][cl * 65 + p];
        out[gi] = 2.f * (h1 * sig + h2 * (1.f - sig));
      }
    }
  }
}

extern "C" void kernel_launch(void* const* d_in, const int* in_sizes, int n_in,
                              void* d_out, int out_size, void* d_ws, size_t ws_size,
                              hipStream_t stream) {
  (void)in_sizes; (void)n_in; (void)out_size;
  const float* x1    = (const float*)d_in[0];
  const float* x2    = (const float*)d_in[1];
  const float* se_w1 = (const float*)d_in[2];
  const float* se_w2 = (const float*)d_in[3];
  const float* gamma = (const float*)d_in[4];
  const float* beta  = (const float*)d_in[5];
  const float* wq    = (const float*)d_in[6];
  const float* bq    = (const float*)d_in[7];
  const float* wk    = (const float*)d_in[8];
  const float* bk    = (const float*)d_in[9];
  const float* wv    = (const float*)d_in[10];
  const float* bv    = (const float*)d_in[11];
  float* out = (float*)d_out;
  char* ws = (char*)d_ws;
  float*  stats = (float*)(ws + STATS_OFF);
  float*  ad    = (float*)(ws + AD_OFF);
  float*  sey   = (float*)(ws + SEY_OFF);
  int*    ccnt  = (int*)(ws + CCNT_OFF);
  ushort* wqb   = (ushort*)(ws + WQB_OFF);
  ushort* wkb   = (ushort*)(ws + WKB_OFF);
  ushort* wvb   = (ushort*)(ws + WVB_OFF);
  ushort* qb    = (ushort*)(ws + Q_OFF);
  ushort* kb    = (ushort*)(ws + K_OFF);
  ushort* vb    = (ushort*)(ws + V_OFF);

  // js split: largest of {8,4,2} whose partials fit the workspace (ws_size fixed per process).
  int jsbits = 1;
  for (int jb = 3; jb >= 2; jb--) {
    size_t need = (size_t)PO_OFF + ((size_t)8 * 4096 * 64 * 2 + (size_t)8 * 4096 * 4) * (1u << jb);
    if (ws_size >= need) { jsbits = jb; break; }
  }
  int njs = 1 << jsbits;
  ushort* pob = (ushort*)(ws + PO_OFF);
  float*  plb = (float*)(ws + PO_OFF + (size_t)8 * njs * 4096 * 64 * 2);

  sc_stats <<<1024, 256, 0, stream>>>(x1, x2, stats, wq, wk, wv, wqb, wkb, wvb);
  sc_prep  <<<1, 256, 0, stream>>>(stats, se_w1, se_w2, gamma, beta, ad, sey, ccnt);
  sc_proj  <<<dim3(64, 3, 4), 256, 0, stream>>>(x1, x2, ad,
                                                wq, bq, wk, bk, wv, bv,
                                                wqb, wkb, wvb, qb, kb, vb);
  sc_flash <<<8 * 16 * njs, 256, 0, stream>>>(qb, kb, vb, x1, x2, sey,
                                              pob, plb, ccnt, out, jsbits);
}

// Round 12
// 150.581 us; speedup vs baseline: 2.5712x; 2.3025x over previous
//
#include <hip/hip_runtime.h>

// B=4, C=64, H=W=64, N=4096, GROUPS=32 (2 ch/group), R=4.
// ws layout (bytes):
#define STATS_OFF 0                       // [1024][5] fp32 partial sums (bc*4+chunk)
#define WQB_OFF   32768                   // bf16 wq*qscale [o][c] 8KB
#define WKB_OFF   40960                   // bf16 wk
#define WVB_OFF   49152                   // bf16 wv
#define Q_OFF     57344                   // [bh][n][c] bf16, 4MB (q pre-scaled)
#define K_OFF     (Q_OFF + 4194304)       // [bh][n][c] bf16, 4MB
#define V_OFF     (K_OFF + 4194304)       // [b][c][n]  bf16, 2MB
#define PO_OFF    (V_OFF + 2097152)       // [bh][js][n][c] bf16 partials, then pl fp32

#define QSCALE 0.18033688f                // 0.125 * log2(e)
// XOR swizzle (8-element granularity) -> balanced LDS bank phases for b128/b64 frag reads
#define SWZ(r) ((((r) & 7) << 3) ^ (((r) & 8) << 1))

typedef __attribute__((ext_vector_type(8))) short  short8;
typedef __attribute__((ext_vector_type(4))) short  s16x4;
typedef __attribute__((ext_vector_type(2))) unsigned int u32x2;
typedef __attribute__((ext_vector_type(4))) float  f32x4;

#if __has_builtin(__builtin_amdgcn_exp2f)
__device__ inline float fexp2(float x) { return __builtin_amdgcn_exp2f(x); }  // raw v_exp_f32
#else
__device__ inline float fexp2(float x) { return exp2f(x); }
#endif

__device__ inline ushort f2b(float f) {   // round-half-up to bf16
  return (ushort)((__float_as_uint(f) + 0x8000u) >> 16);
}
__device__ inline unsigned pack2(float x, float y) {  // bf16(x) | bf16(y)<<16
  unsigned ux = __float_as_uint(x) + 0x8000u;
  unsigned uy = __float_as_uint(y) + 0x8000u;
  return __builtin_amdgcn_perm(uy, ux, 0x07060302);
}
__device__ inline float b2f(ushort u) { return __uint_as_float(((unsigned)u) << 16); }

__device__ inline f32x4 mfma16(short8 a, short8 b, f32x4 c) {
  return __builtin_amdgcn_mfma_f32_16x16x32_bf16(a, b, c, 0, 0, 0);
}

__device__ inline float wsum64(float v) {
  #pragma unroll
  for (int o = 32; o > 0; o >>= 1) v += __shfl_down(v, o, 64);
  return v;
}

// ---------------- kernel 1: per-(b,c) partial sums + bf16 weight conversion ----------------
__global__ __launch_bounds__(256) void sc_stats(const float* __restrict__ x1,
                                                const float* __restrict__ x2,
                                                float* __restrict__ stats,
                                                const float* __restrict__ wq,
                                                const float* __restrict__ wk,
                                                const float* __restrict__ wv,
                                                ushort* __restrict__ wqb,
                                                ushort* __restrict__ wkb,
                                                ushort* __restrict__ wvb) {
  int blk = blockIdx.x, t = threadIdx.x;  // 1024 = bc*4 + chunk
  int bc = blk >> 2, chunk = blk & 3;
  const float4* p1 = (const float4*)(x1 + (size_t)bc * 4096 + chunk * 1024);
  const float4* p2 = (const float4*)(x2 + (size_t)bc * 4096 + chunk * 1024);
  float4 a = p1[t], b = p2[t];
  float s1 = a.x + a.y + a.z + a.w;
  float q1 = a.x*a.x + a.y*a.y + a.z*a.z + a.w*a.w;
  float s2 = b.x + b.y + b.z + b.w;
  float q2 = b.x*b.x + b.y*b.y + b.z*b.z + b.w*b.w;
  float p12 = a.x*b.x + a.y*b.y + a.z*b.z + a.w*b.w;
  s1 = wsum64(s1); q1 = wsum64(q1); s2 = wsum64(s2); q2 = wsum64(q2); p12 = wsum64(p12);
  __shared__ float red[4][5];
  int w = t >> 6, ln = t & 63;
  if (ln == 0) { red[w][0] = s1; red[w][1] = q1; red[w][2] = s2; red[w][3] = q2; red[w][4] = p12; }
  __syncthreads();
  if (t < 5) {
    float acc = 0;
    #pragma unroll
    for (int ww = 0; ww < 4; ww++) acc += red[ww][t];
    stats[(size_t)blk * 5 + t] = acc;
  }
  if (blk >= 976) {     // parallel bf16 weight conversion (independent of stats)
    int idx = (blk - 976) * 256 + t;
    int arr = idx >> 12, e = idx & 4095;
    if (arr == 0)      wqb[e] = f2b(wq[e] * QSCALE);
    else if (arr == 1) wkb[e] = f2b(wk[e]);
    else               wvb[e] = f2b(wv[e]);
  }
}

// ------------- kernel 2: GN + 1x1 conv projections via MFMA, inline GN fold -------------
// Each block recomputes its (src,b) GN fold from stats (5KB read) — no sc_prep dispatch.
__global__ __launch_bounds__(256) void sc_proj(const float* __restrict__ x1, const float* __restrict__ x2,
    const float* __restrict__ stats,
    const float* __restrict__ gamma, const float* __restrict__ beta,
    const float* __restrict__ wq, const float* __restrict__ bq,
    const float* __restrict__ wk, const float* __restrict__ bk,
    const float* __restrict__ wv, const float* __restrict__ bv,
    const ushort* __restrict__ wqb, const ushort* __restrict__ wkb, const ushort* __restrict__ wvb,
    ushort* __restrict__ qout, ushort* __restrict__ kout, ushort* __restrict__ vout) {
  int pt = blockIdx.x, src = blockIdx.y, b = blockIdx.z, t = threadIdx.x;
  __shared__ ushort xlds[64 * 66];   // xn tile [p][c], bf16
  __shared__ ushort olds[64 * 66];   // output assembly tile
  __shared__ float sS[64], sQ[64], sa[64], sd[64], sbias[2][64];
  if (t < 64) {                      // per-channel sums for this src
    float a1 = 0, a2 = 0, a3 = 0, a4 = 0, a5 = 0;
    #pragma unroll
    for (int ch = 0; ch < 4; ch++) {
      const float* sp = stats + (size_t)((b * 64 + t) * 4 + ch) * 5;
      a1 += sp[0]; a2 += sp[1]; a3 += sp[2]; a4 += sp[3]; a5 += sp[4];
    }
    float S, Q;
    if (src == 0)      { S = a1 + a3; Q = a2 + a4 + 2.f * a5; }
    else if (src == 1) { S = a1; Q = a2; }
    else               { S = a3; Q = a4; }
    sS[t] = S; sQ[t] = Q;
  }
  __syncthreads();
  if (t < 64) {                      // 2-channel group fold
    float S = sS[t] + sS[t ^ 1], Q = sQ[t] + sQ[t ^ 1];
    float mean = S * (1.f / 8192.f);
    float var  = Q * (1.f / 8192.f) - mean * mean;
    float rstd = rsqrtf(var + 1e-6f);
    float a = gamma[t] * rstd;
    sa[t] = a;
    sd[t] = beta[t] - mean * a;
  }
  __syncthreads();
  {
    int c = t >> 2, pq = (t & 3) * 16;
    const float* px1 = x1 + ((size_t)(b*64 + c))*4096 + pt*64 + pq;
    const float* px2 = x2 + ((size_t)(b*64 + c))*4096 + pt*64 + pq;
    float av = sa[c];
    #pragma unroll
    for (int k4 = 0; k4 < 4; k4++) {
      float4 v1 = *(const float4*)(px1 + 4*k4);
      float xv[4];
      if (src == 1) { xv[0]=v1.x; xv[1]=v1.y; xv[2]=v1.z; xv[3]=v1.w; }
      else {
        float4 v2 = *(const float4*)(px2 + 4*k4);
        if (src == 2) { xv[0]=v2.x; xv[1]=v2.y; xv[2]=v2.z; xv[3]=v2.w; }
        else { xv[0]=v1.x+v2.x; xv[1]=v1.y+v2.y; xv[2]=v1.z+v2.z; xv[3]=v1.w+v2.w; }
      }
      #pragma unroll
      for (int k = 0; k < 4; k++)
        xlds[(pq + 4*k4 + k)*66 + c] = f2b(av * xv[k]);
    }
  }
  int nbias = (src == 0) ? 64 : 128;
  if (t < nbias) {                   // bias' = W*d + bias (parallel across all 768 blocks)
    int proj = t >> 6, o = t & 63;
    const float* W  = (src == 0) ? wv : (proj == 0 ? wq : wk);
    const float* bs = (src == 0) ? bv : (proj == 0 ? bq : bk);
    float acc = bs[o];
    for (int cc = 0; cc < 64; cc++) acc += W[o*64+cc] * sd[cc];
    if (src != 0 && proj == 0) acc *= QSCALE;
    sbias[proj][o] = acc;
  }
  __syncthreads();
  int wave = t >> 6, lane = t & 63, quad = lane >> 4, l15 = lane & 15;
  int orow = t >> 2, ocol = (t & 3) * 16;   // coalesced write-out mapping
  if (src == 0) {
    const ushort* ap = wvb + (wave*16 + l15)*64 + quad*8;
    short8 a0 = *(const short8*)ap;
    short8 a1 = *(const short8*)(ap + 32);
    f32x4 cinit;
    #pragma unroll
    for (int r = 0; r < 4; r++) cinit[r] = sbias[0][wave*16 + quad*4 + r];
    #pragma unroll
    for (int s = 0; s < 4; s++) {
      const ushort* bp = xlds + (s*16 + l15)*66 + quad*8;
      short8 b0 = *(const short8*)bp;
      short8 b1 = *(const short8*)(bp + 32);
      f32x4 acc = mfma16(a0, b0, cinit);
      acc = mfma16(a1, b1, acc);
      #pragma unroll
      for (int r = 0; r < 4; r++)
        olds[(wave*16 + quad*4 + r)*66 + s*16 + l15] = f2b(acc[r]);   // [o][p]
    }
    __syncthreads();
    uint4 w0 = *(const uint4*)&olds[orow*66 + ocol];
    uint4 w1 = *(const uint4*)&olds[orow*66 + ocol + 8];
    ushort* dst = vout + ((size_t)(b*64 + orow))*4096 + pt*64 + ocol;
    *(uint4*)dst = w0; *(uint4*)(dst + 8) = w1;
  } else {
    int bh = b*2 + (src - 1);
    const ushort* ap = xlds + (wave*16 + l15)*66 + quad*8;
    short8 a0 = *(const short8*)ap;
    short8 a1 = *(const short8*)(ap + 32);
    #pragma unroll
    for (int proj = 0; proj < 2; proj++) {
      const ushort* Wb = proj == 0 ? wqb : wkb;
      ushort* dst = proj == 0 ? qout : kout;
      #pragma unroll
      for (int s = 0; s < 4; s++) {
        const ushort* bp = Wb + (s*16 + l15)*64 + quad*8;
        short8 b0 = *(const short8*)bp;
        short8 b1 = *(const short8*)(bp + 32);
        float bb = sbias[proj][s*16 + l15];
        f32x4 acc = {bb, bb, bb, bb};
        acc = mfma16(a0, b0, acc);
        acc = mfma16(a1, b1, acc);
        #pragma unroll
        for (int r = 0; r < 4; r++)
          olds[(wave*16 + quad*4 + r)*66 + s*16 + l15] = f2b(acc[r]);  // [p][o]
      }
      __syncthreads();
      uint4 w0 = *(const uint4*)&olds[orow*66 + ocol];
      uint4 w1 = *(const uint4*)&olds[orow*66 + ocol + 8];
      ushort* dp = dst + ((size_t)bh*4096 + pt*64 + orow)*64 + ocol;
      *(uint4*)dp = w0; *(uint4*)(dp + 8) = w1;
      if (proj == 0) __syncthreads();   // olds reused by proj 1
    }
  }
}

// ------------- kernel 3: flash attention, i=64/wave, XOR-swizzled LDS, S^T + _1k -------------
// grid 8*16*njs. R8-proven body, untouched. launch_bounds(256,2): VGPR cap 128, uses 108.
__global__ __launch_bounds__(256, 2) void sc_flash(const ushort* __restrict__ qg,
                                                   const ushort* __restrict__ kg,
                                                   const ushort* __restrict__ vg,
                                                   ushort* __restrict__ po,
                                                   float* __restrict__ pl,
                                                   int jsbits) {
  int blk = blockIdx.x;
  int bh = blk & 7, rest = blk >> 3;
  int njs = 1 << jsbits, njt = 64 >> jsbits;
  int js = rest & (njs - 1), itile = rest >> jsbits;   // itile 0..15
  int jbase = js * (njt << 6);
  int b = bh >> 1;
  int t = threadIdx.x, wave = t >> 6, lane = t & 63, quad = lane >> 4, l15 = lane & 15;
  int i0 = itile * 256 + wave * 64;

  __shared__ ushort Klds[64 * 64];       // [j][c^swz(j)]
  __shared__ ushort Vlds[64 * 64];       // [c][j^swz(c)]

  short8 Qb[4][2];
  #pragma unroll
  for (int ib = 0; ib < 4; ib++) {
    const ushort* qp = qg + ((size_t)bh * 4096 + i0 + ib * 16 + l15) * 64 + quad * 8;
    Qb[ib][0] = *(const short8*)qp;
    Qb[ib][1] = *(const short8*)(qp + 32);
  }

  f32x4 O[4][4]; const f32x4 zero4 = {0.f, 0.f, 0.f, 0.f};
  #pragma unroll
  for (int ib = 0; ib < 4; ib++)
    #pragma unroll
    for (int cb = 0; cb < 4; cb++) O[ib][cb] = zero4;
  float lsum[4] = {0.f, 0.f, 0.f, 0.f};

  int sr = t >> 2, sc = (t & 3) * 16;
  int swzs = SWZ(sr);
  int swzl = SWZ(l15);
  const ushort* ksrc = kg + ((size_t)bh * 4096 + jbase + sr) * 64 + sc;
  const ushort* vsrc = vg + ((size_t)(b * 64 + sr)) * 4096 + jbase + sc;
  ushort* kd0 = Klds + sr * 64 + (sc ^ swzs);
  ushort* kd1 = Klds + sr * 64 + ((sc + 8) ^ swzs);
  ushort* vd0 = Vlds + sr * 64 + (sc ^ swzs);
  ushort* vd1 = Vlds + sr * 64 + ((sc + 8) ^ swzs);

  uint4 kr0 = *(const uint4*)ksrc, kr1 = *(const uint4*)(ksrc + 8);
  uint4 vr0 = *(const uint4*)vsrc, vr1 = *(const uint4*)(vsrc + 8);
  ksrc += 4096; vsrc += 64;

  #pragma unroll 1
  for (int jt = 0; jt < njt; jt++) {
    __syncthreads();
    *(uint4*)kd0 = kr0; *(uint4*)kd1 = kr1;
    *(uint4*)vd0 = vr0; *(uint4*)vd1 = vr1;
    __syncthreads();
    if (jt + 1 < njt) {
      kr0 = *(const uint4*)ksrc; kr1 = *(const uint4*)(ksrc + 8);
      vr0 = *(const uint4*)vsrc; vr1 = *(const uint4*)(vsrc + 8);
      ksrc += 4096; vsrc += 64;
    }

    #pragma unroll
    for (int s = 0; s < 4; s++) {
      int rowK = (s * 16 + l15) * 64;
      short8 ka0 = *(const short8*)&Klds[rowK + ((quad * 8) ^ swzl)];
      short8 ka1 = *(const short8*)&Klds[rowK + ((quad * 8 + 32) ^ swzl)];
      f32x4 S[4];
      #pragma unroll
      for (int ib = 0; ib < 4; ib++) {
        f32x4 acc = mfma16(ka0, Qb[ib][0], zero4);
        S[ib] = mfma16(ka1, Qb[ib][1], acc);
      }
      s16x4 vbf[4];
      #pragma unroll
      for (int cb = 0; cb < 4; cb++)
        vbf[cb] = *(const s16x4*)&Vlds[(cb * 16 + l15) * 64 + ((s * 16 + quad * 4) ^ swzl)];
      #pragma unroll
      for (int ib = 0; ib < 4; ib++) {
        float p0 = fexp2(S[ib][0]);
        float p1 = fexp2(S[ib][1]);
        float p2 = fexp2(S[ib][2]);
        float p3 = fexp2(S[ib][3]);
        lsum[ib] += (p0 + p1) + (p2 + p3);
        u32x2 wpk = {pack2(p0, p1), pack2(p2, p3)};
        s16x4 Pb = __builtin_bit_cast(s16x4, wpk);
        #pragma unroll
        for (int cb = 0; cb < 4; cb++)
          O[ib][cb] = __builtin_amdgcn_mfma_f32_16x16x16bf16_1k(Pb, vbf[cb], O[ib][cb], 0, 0, 0);
      }
    }
  }

  size_t slice = (size_t)(bh * njs + js) * 4096;
  #pragma unroll
  for (int ib = 0; ib < 4; ib++) {
    float lv = lsum[ib];
    lv += __shfl_xor(lv, 16, 64);
    lv += __shfl_xor(lv, 32, 64);
    if (quad == 0) pl[slice + i0 + ib * 16 + l15] = lv;
    #pragma unroll
    for (int cb = 0; cb < 4; cb++)
      #pragma unroll
      for (int r = 0; r < 4; r++)
        po[(slice + i0 + ib * 16 + quad * 4 + r) * 64 + cb * 16 + l15] = f2b(O[ib][cb][r]);
  }
}

// ------------- kernel 4: partial reduce + normalize + SE-gated blend, inline SE -------------
// grid (64 itile, 4 b, 2 chalf). Each block recomputes its b's SE sigmoid from stats.
__global__ __launch_bounds__(256) void sc_combine(const float* __restrict__ x1, const float* __restrict__ x2,
                                                  const ushort* __restrict__ po, const float* __restrict__ pl,
                                                  const float* __restrict__ stats,
                                                  const float* __restrict__ w1, const float* __restrict__ w2,
                                                  float* __restrict__ out, int jsbits) {
  int njs = 1 << jsbits;
  int itile = blockIdx.x, b = blockIdx.y, ch = blockIdx.z, t = threadIdx.x;
  __shared__ float hl[2][32 * 65];   // [head][c-local][p]
  __shared__ float smu[64], syr[4], ssey[64];
  if (t < 64) {                      // spatial mean of x = x1+x2 for channel t of batch b
    float s = 0;
    #pragma unroll
    for (int chk = 0; chk < 4; chk++) {
      const float* sp = stats + (size_t)((b * 64 + t) * 4 + chk) * 5;
      s += sp[0] + sp[2];
    }
    smu[t] = s * (1.f / 4096.f);
  }
  __syncthreads();
  if (t < 4) {                       // SE layer 1 + relu
    float acc = 0.f;
    for (int cc = 0; cc < 64; cc++) acc += w1[t*64+cc] * smu[cc];
    syr[t] = fmaxf(acc, 0.f);
  }
  __syncthreads();
  if (t < 64) {                      // SE layer 2 + sigmoid
    float acc = 0.f;
    #pragma unroll
    for (int r = 0; r < 4; r++) acc += w2[t*4+r] * syr[r];
    ssey[t] = 1.f / (1.f + fexp2(-acc * 1.44269504f));
  }
  #pragma unroll
  for (int head = 0; head < 2; head++) {
    int bh = b * 2 + head;
    int i = t >> 2, c8 = (t & 3) * 8;
    float sum[8];
    #pragma unroll
    for (int k = 0; k < 8; k++) sum[k] = 0.f;
    float lacc = 0.f;
    for (int js = 0; js < njs; js++) {
      size_t base = ((size_t)(bh * njs + js)) * 4096;
      uint4 u = *(const uint4*)(po + base * 64 + (size_t)(itile * 64 + i) * 64 + ch * 32 + c8);
      const ushort* us = (const ushort*)&u;
      #pragma unroll
      for (int k = 0; k < 8; k++) sum[k] += b2f(us[k]);
      lacc += pl[base + itile * 64 + i];
    }
    float inv = 1.f / lacc;
    #pragma unroll
    for (int k = 0; k < 8; k++) hl[head][(c8 + k) * 65 + i] = sum[k] * inv;
  }
  __syncthreads();
  #pragma unroll
  for (int it = 0; it < 8; it++) {
    int idx = it * 256 + t;
    int cl = idx >> 6, p = idx & 63;
    int c = ch * 32 + cl;
    size_t gi = ((size_t)(b * 64 + c)) * 4096 + itile * 64 + p;
    float xv = x1[gi] + x2[gi];
    float sig = 1.f / (1.f + fexp2(-xv * ssey[c] * 1.44269504f));
    float h1 = hl[0][cl * 65 + p], h2 = hl[1][cl * 65 + p];
    out[gi] = 2.f * (h1 * sig + h2 * (1.f - sig));
  }
}

extern "C" void kernel_launch(void* const* d_in, const int* in_sizes, int n_in,
                              void* d_out, int out_size, void* d_ws, size_t ws_size,
                              hipStream_t stream) {
  (void)in_sizes; (void)n_in; (void)out_size;
  const float* x1    = (const float*)d_in[0];
  const float* x2    = (const float*)d_in[1];
  const float* se_w1 = (const float*)d_in[2];
  const float* se_w2 = (const float*)d_in[3];
  const float* gamma = (const float*)d_in[4];
  const float* beta  = (const float*)d_in[5];
  const float* wq    = (const float*)d_in[6];
  const float* bq    = (const float*)d_in[7];
  const float* wk    = (const float*)d_in[8];
  const float* bk    = (const float*)d_in[9];
  const float* wv    = (const float*)d_in[10];
  const float* bv    = (const float*)d_in[11];
  float* out = (float*)d_out;
  char* ws = (char*)d_ws;
  float*  stats = (float*)(ws + STATS_OFF);
  ushort* wqb   = (ushort*)(ws + WQB_OFF);
  ushort* wkb   = (ushort*)(ws + WKB_OFF);
  ushort* wvb   = (ushort*)(ws + WVB_OFF);
  ushort* qb    = (ushort*)(ws + Q_OFF);
  ushort* kb    = (ushort*)(ws + K_OFF);
  ushort* vb    = (ushort*)(ws + V_OFF);

  // js split: largest of {8,4,2} whose partials fit the workspace (ws_size fixed per process).
  int jsbits = 1;
  for (int jb = 3; jb >= 2; jb--) {
    size_t need = (size_t)PO_OFF + ((size_t)8 * 4096 * 64 * 2 + (size_t)8 * 4096 * 4) * (1u << jb);
    if (ws_size >= need) { jsbits = jb; break; }
  }
  int njs = 1 << jsbits;
  ushort* pob = (ushort*)(ws + PO_OFF);
  float*  plb = (float*)(ws + PO_OFF + (size_t)8 * njs * 4096 * 64 * 2);

  sc_stats  <<<1024, 256, 0, stream>>>(x1, x2, stats, wq, wk, wv, wqb, wkb, wvb);
  sc_proj   <<<dim3(64, 3, 4), 256, 0, stream>>>(x1, x2, stats, gamma, beta,
                                                 wq, bq, wk, bk, wv, bv,
                                                 wqb, wkb, wvb, qb, kb, vb);
  sc_flash  <<<8 * 16 * njs, 256, 0, stream>>>(qb, kb, vb, pob, plb, jsbits);
  sc_combine<<<dim3(64, 4, 2), 256, 0, stream>>>(x1, x2, pob, plb, stats,
                                                 se_w1, se_w2, out, jsbits);
}